// Round 1
// baseline (1421.336 us; speedup 1.0000x reference)
//
#include <hip/hip_runtime.h>

static constexpr int NSIDE = 48;
static constexpr int NVOX  = NSIDE * NSIDE * NSIDE;   // 110592
static constexpr float SCALE = 0.041875863808787856f; // ONE_OVER_DIFF_TOT * DIFF_Q

// Neighbor offsets = -SHIFTS (jnp.roll(q, s) => nb[p] = q[p - s]).
// Order matches D_INV: 6 faces (1), 12 edges (1/sqrt2), 8 corners (1/sqrt3).
__device__ __constant__ int c_ox[26] = { 1,-1, 0, 0, 0, 0,
                                         1,-1, 1,-1, 1,-1, 1,-1, 0, 0, 0, 0,
                                         1, 1, 1, 1,-1,-1,-1,-1 };
__device__ __constant__ int c_oy[26] = { 0, 0, 1,-1, 0, 0,
                                         1, 1,-1,-1, 0, 0, 0, 0, 1,-1, 1,-1,
                                         1, 1,-1,-1, 1, 1,-1,-1 };
__device__ __constant__ int c_oz[26] = { 0, 0, 0, 0, 1,-1,
                                         0, 0, 0, 0, 1, 1,-1,-1, 1, 1,-1,-1,
                                         1,-1, 1,-1, 1,-1, 1,-1 };
__device__ __constant__ float c_dinv[26] = {
    1.f, 1.f, 1.f, 1.f, 1.f, 1.f,
    0.70710678118654752f, 0.70710678118654752f, 0.70710678118654752f, 0.70710678118654752f,
    0.70710678118654752f, 0.70710678118654752f, 0.70710678118654752f, 0.70710678118654752f,
    0.70710678118654752f, 0.70710678118654752f, 0.70710678118654752f, 0.70710678118654752f,
    0.57735026918962576f, 0.57735026918962576f, 0.57735026918962576f, 0.57735026918962576f,
    0.57735026918962576f, 0.57735026918962576f, 0.57735026918962576f, 0.57735026918962576f };

__device__ __forceinline__ float fast_tanh(float x) {
    // tanh(x) = 1 - 2/(exp2(2*log2e*x)+1); exact at +-inf saturation.
    float e = __builtin_amdgcn_exp2f(x * 2.8853900817779268f);
    float r = __builtin_amdgcn_rcpf(e + 1.0f);
    return fmaf(-2.0f, r, 1.0f);
}

// LDS weight layout (floats):
//  W0:[0,64) b0:[64,80) W1:[80,336) b1:[336,352) W2:[352,608) b2:[608,624)
//  W3:[624,880) b3:[880,896) Wout:[896,912) bout:[912]
__global__ __launch_bounds__(256)
void automaton_kernel(const float* __restrict__ q,
                      const float* __restrict__ W0, const float* __restrict__ b0,
                      const float* __restrict__ W1, const float* __restrict__ b1,
                      const float* __restrict__ W2, const float* __restrict__ b2,
                      const float* __restrict__ W3, const float* __restrict__ b3,
                      const float* __restrict__ Wout, const float* __restrict__ bout,
                      float* __restrict__ out)
{
    __shared__ __align__(16) float sw[916];
    const int t = threadIdx.x;
    if (t <  64) sw[      t] = W0[t];
    if (t <  16) sw[ 64 + t] = b0[t];
                 sw[ 80 + t] = W1[t];
    if (t <  16) sw[336 + t] = b1[t];
                 sw[352 + t] = W2[t];
    if (t <  16) sw[608 + t] = b2[t];
                 sw[624 + t] = W3[t];
    if (t <  16) sw[880 + t] = b3[t];
    if (t <  16) sw[896 + t] = Wout[t];
    if (t ==  0) sw[912]     = bout[0];
    __syncthreads();

    const int gid  = blockIdx.x * 256 + t;          // 0 .. 221183
    const int vox  = gid >> 1;
    const int half = gid & 1;

    const int z = vox % NSIDE;
    const int y = (vox / NSIDE) % NSIDE;
    const int x = vox / (NSIDE * NSIDE);
    const int xm = (x == 0) ? NSIDE - 1 : x - 1;
    const int xp = (x == NSIDE - 1) ? 0 : x + 1;
    const int ym = (y == 0) ? NSIDE - 1 : y - 1;
    const int yp = (y == NSIDE - 1) ? 0 : y + 1;
    const int zm = (z == 0) ? NSIDE - 1 : z - 1;
    const int zp = (z == NSIDE - 1) ? 0 : z + 1;

    const float2 own = reinterpret_cast<const float2*>(q)[vox];
    const float o0 = own.x, o1 = own.y;

    float sum = 0.0f;
    #pragma unroll 1
    for (int k = half * 13; k < half * 13 + 13; ++k) {
        const int ox = c_ox[k], oy = c_oy[k], oz = c_oz[k];
        const int nx = (ox < 0) ? xm : ((ox > 0) ? xp : x);
        const int ny = (oy < 0) ? ym : ((oy > 0) ? yp : y);
        const int nz = (oz < 0) ? zm : ((oz > 0) ? zp : z);
        const float2 nbq = reinterpret_cast<const float2*>(q)[(nx * NSIDE + ny) * NSIDE + nz];
        const float n0 = nbq.x, n1 = nbq.y;

        // layer 0: 4 -> 16, both orderings share the weight load
        float ha[16], hb[16];
        #pragma unroll
        for (int i = 0; i < 16; ++i) {
            const float4 w = *reinterpret_cast<const float4*>(&sw[i * 4]);
            const float bb = sw[64 + i];
            float pa = fmaf(w.x, o0, fmaf(w.y, o1, fmaf(w.z, n0, fmaf(w.w, n1, bb))));
            float pb = fmaf(w.x, n0, fmaf(w.y, n1, fmaf(w.z, o0, fmaf(w.w, o1, bb))));
            ha[i] = fast_tanh(pa);
            hb[i] = fast_tanh(pb);
        }

        // layers 1..3: 16 -> 16
        #pragma unroll
        for (int l = 0; l < 3; ++l) {
            const int wb = 80 + l * 272;   // weights at wb, bias at wb+256
            float na[16], nb2[16];
            #pragma unroll
            for (int i = 0; i < 16; ++i) {
                float aa = sw[wb + 256 + i];
                float ab = aa;
                #pragma unroll
                for (int kk = 0; kk < 4; ++kk) {
                    const float4 w = *reinterpret_cast<const float4*>(&sw[wb + i * 16 + kk * 4]);
                    aa = fmaf(w.x, ha[4 * kk + 0], aa);
                    aa = fmaf(w.y, ha[4 * kk + 1], aa);
                    aa = fmaf(w.z, ha[4 * kk + 2], aa);
                    aa = fmaf(w.w, ha[4 * kk + 3], aa);
                    ab = fmaf(w.x, hb[4 * kk + 0], ab);
                    ab = fmaf(w.y, hb[4 * kk + 1], ab);
                    ab = fmaf(w.z, hb[4 * kk + 2], ab);
                    ab = fmaf(w.w, hb[4 * kk + 3], ab);
                }
                na[i]  = fast_tanh(aa);
                nb2[i] = fast_tanh(ab);
            }
            #pragma unroll
            for (int i = 0; i < 16; ++i) { ha[i] = na[i]; hb[i] = nb2[i]; }
        }

        // output layer: 16 -> 1
        float oa = sw[912], ob = sw[912];
        #pragma unroll
        for (int kk = 0; kk < 4; ++kk) {
            const float4 w = *reinterpret_cast<const float4*>(&sw[896 + kk * 4]);
            oa = fmaf(w.x, ha[4 * kk + 0], oa);
            oa = fmaf(w.y, ha[4 * kk + 1], oa);
            oa = fmaf(w.z, ha[4 * kk + 2], oa);
            oa = fmaf(w.w, ha[4 * kk + 3], oa);
            ob = fmaf(w.x, hb[4 * kk + 0], ob);
            ob = fmaf(w.y, hb[4 * kk + 1], ob);
            ob = fmaf(w.z, hb[4 * kk + 2], ob);
            ob = fmaf(w.w, hb[4 * kk + 3], ob);
        }
        const float tr  = fast_tanh(oa - ob);
        const float fac = (tr < 0.0f) ? o0 : n0;
        sum = fmaf(tr * fac, c_dinv[k], sum);
    }

    // pair-reduce the two halves of this voxel (lanes gid and gid^1)
    sum += __shfl_xor(sum, 1);

    if (half == 0) {
        float2 r;
        r.x = fmaf(sum, SCALE, o0);
        r.y = o1;
        reinterpret_cast<float2*>(out)[vox] = r;
    }
}

extern "C" void kernel_launch(void* const* d_in, const int* in_sizes, int n_in,
                              void* d_out, int out_size, void* d_ws, size_t ws_size,
                              hipStream_t stream) {
    const float* q    = (const float*)d_in[0];
    const float* W0   = (const float*)d_in[1];
    const float* b0   = (const float*)d_in[2];
    const float* W1   = (const float*)d_in[3];
    const float* b1   = (const float*)d_in[4];
    const float* W2   = (const float*)d_in[5];
    const float* b2   = (const float*)d_in[6];
    const float* W3   = (const float*)d_in[7];
    const float* b3   = (const float*)d_in[8];
    const float* Wout = (const float*)d_in[9];
    const float* bout = (const float*)d_in[10];
    float* out = (float*)d_out;

    const int threads = 256;
    const int blocks  = (NVOX * 2) / threads;  // 864
    automaton_kernel<<<dim3(blocks), dim3(threads), 0, stream>>>(
        q, W0, b0, W1, b1, W2, b2, W3, b3, Wout, bout, out);
}